// Round 9
// baseline (177.656 us; speedup 1.0000x reference)
//
#include <hip/hip_runtime.h>
#include <hip/hip_bf16.h>
#include <math.h>

// Problem constants (match reference)
#define BB 2
#define LL 4096
#define DD 128
#define ED 256
#define NN 16
#define KK 4
#define RR 8
#define HH 256
#define NT (BB*LL)          // 8192 tokens
#define NC 128              // tail tiles (32 tokens)
#define LC 32               // tail tile length
#define NCS 256             // scan chunks (16 tokens)
#define LCS 16              // scan chunk length

#define LOG2E 1.4426950408889634f
#define LN2F  0.6931471805599453f

typedef __attribute__((ext_vector_type(8))) short short8;
typedef __attribute__((ext_vector_type(8))) unsigned short ushort8v;
typedef __attribute__((ext_vector_type(4))) float floatx4;

__device__ __forceinline__ unsigned short f2bf(float f) {
  unsigned int b = __builtin_bit_cast(unsigned int, f);
  b += 0x7FFFu + ((b >> 16) & 1u);           // round-to-nearest-even
  return (unsigned short)(b >> 16);
}

__device__ __forceinline__ float exp2_fast(float x) {
#if __has_builtin(__builtin_amdgcn_exp2f)
  return __builtin_amdgcn_exp2f(x);
#else
  return exp2f(x);
#endif
}

__device__ __forceinline__ ushort8v pack8(const float4& v0, const float4& v1) {
  ushort8v p;
  p[0]=f2bf(v0.x); p[1]=f2bf(v0.y); p[2]=f2bf(v0.z); p[3]=f2bf(v0.w);
  p[4]=f2bf(v1.x); p[5]=f2bf(v1.y); p[6]=f2bf(v1.z); p[7]=f2bf(v1.w);
  return p;
}

// ---------------------------------------------------------------------------
// prep_k: one-time fp32 -> bf16 conversion of all weight matrices
// (unchanged from round 8).
// ---------------------------------------------------------------------------
#define S_IN  65536
#define S_XP  10240
#define S_OUT 32768
#define S_F1  32768
#define S_F2  32768
__global__ __launch_bounds__(256) void prep_k(
    const float* __restrict__ in_w, const float* __restrict__ xpw,
    const float* __restrict__ out_w, const float* __restrict__ fc1_w,
    const float* __restrict__ fc2_w, unsigned short* __restrict__ wb) {
  const int o = (blockIdx.x*256 + threadIdx.x) * 8;
  const float* src;
  int off;
  if (o < S_IN)                          { src = in_w;  off = o; }
  else if (o < S_IN+S_XP)                { src = xpw;   off = o - S_IN; }
  else if (o < S_IN+S_XP+S_OUT)          { src = out_w; off = o - S_IN - S_XP; }
  else if (o < S_IN+S_XP+S_OUT+S_F1)     { src = fc1_w; off = o - S_IN - S_XP - S_OUT; }
  else                                   { src = fc2_w; off = o - S_IN - S_XP - S_OUT - S_F1; }
  const float4 v0 = *(const float4*)(src + off);
  const float4 v1 = *(const float4*)(src + off + 4);
  *(ushort8v*)(wb + o) = pack8(v0, v1);
}

// ---------------------------------------------------------------------------
// scan1n: scan1m + (1) 16-thr/row LN (304 active vs 128), (2) P2 waves own
// 4 n-tiles x BOTH m-tiles (halves B-loads at same MFMA count), (3) cheap
// log2-based softplus (6 ops vs ~25 for log1pf+expf), (4) 1-token register
// prefetch of the P5P6 scan-chain LDS reads.
// 16-token chunks, 512 blocks x 512 threads, 2 blocks/CU. 4 barriers.
// LDS 43.6 KB (same map as scan1m).
// ---------------------------------------------------------------------------
__global__ __launch_bounds__(512, 4) void scan1n_k(
    const float* __restrict__ x,
    const float* __restrict__ g1, const float* __restrict__ b1,
    const float* __restrict__ g2, const float* __restrict__ b2,
    const unsigned short* __restrict__ wb_in,
    const float* __restrict__ cw, const float* __restrict__ cb,
    const unsigned short* __restrict__ wb_xp,
    const float* __restrict__ dtw, const float* __restrict__ dtb,
    const float* __restrict__ A_log,
    float* __restrict__ uc, float* __restrict__ dbc,
    float* __restrict__ delta, float* __restrict__ gate,
    float* __restrict__ cA, float* __restrict__ cH) {
  __shared__ __align__(16) unsigned char SM[44624];
  auto Atile = reinterpret_cast<unsigned short(*)[136]>(SM);
  auto As    = reinterpret_cast<unsigned short(*)[264]>(SM);
  auto ubuf  = reinterpret_cast<float(*)[257]>(SM + 8704);
  auto sdbc  = reinterpret_cast<float(*)[40]>(SM + 8704);
  auto sus   = reinterpret_cast<float(*)[256]>(SM + 28240);

  const int c2 = blockIdx.x, b = blockIdx.y;
  const int tid = threadIdx.x;
  const int t0 = b*LL + c2*LCS;
  const int wave = tid >> 6, lane = tid & 63;
  const int quad = lane >> 4, l16 = lane & 15;

  // --- P1: double-LN of x rows (t0-3 .. t0+15); 16 thr/row, 8 elems each ---
  {
    const int lr = tid >> 4, le = (tid & 15) * 8;   // lr 0..31
    if (lr < 19 && !(c2 == 0 && lr < 3)) {
      const float* Ap = x + (size_t)(t0 - 3 + lr)*DD + le;
      float4 a0 = *(const float4*)(Ap);
      float4 a1 = *(const float4*)(Ap + 4);
      float s  = a0.x + a0.y + a0.z + a0.w + a1.x + a1.y + a1.z + a1.w;
      float sq = a0.x*a0.x + a0.y*a0.y + a0.z*a0.z + a0.w*a0.w
               + a1.x*a1.x + a1.y*a1.y + a1.z*a1.z + a1.w*a1.w;
      s += __shfl_xor(s, 1);  s += __shfl_xor(s, 2);
      s += __shfl_xor(s, 4);  s += __shfl_xor(s, 8);
      sq += __shfl_xor(sq, 1); sq += __shfl_xor(sq, 2);
      sq += __shfl_xor(sq, 4); sq += __shfl_xor(sq, 8);
      const float m1 = s * (1.f/128.f);
      const float rs1 = rsqrtf(sq*(1.f/128.f) - m1*m1 + 1e-5f);
      const float4 ga0 = *(const float4*)(g1 + le);
      const float4 ga1 = *(const float4*)(g1 + le + 4);
      const float4 bb0 = *(const float4*)(b1 + le);
      const float4 bb1 = *(const float4*)(b1 + le + 4);
      float4 v0, v1;
      v0.x = (a0.x - m1)*rs1*ga0.x + bb0.x;
      v0.y = (a0.y - m1)*rs1*ga0.y + bb0.y;
      v0.z = (a0.z - m1)*rs1*ga0.z + bb0.z;
      v0.w = (a0.w - m1)*rs1*ga0.w + bb0.w;
      v1.x = (a1.x - m1)*rs1*ga1.x + bb1.x;
      v1.y = (a1.y - m1)*rs1*ga1.y + bb1.y;
      v1.z = (a1.z - m1)*rs1*ga1.z + bb1.z;
      v1.w = (a1.w - m1)*rs1*ga1.w + bb1.w;
      float s2  = v0.x + v0.y + v0.z + v0.w + v1.x + v1.y + v1.z + v1.w;
      float sq2 = v0.x*v0.x + v0.y*v0.y + v0.z*v0.z + v0.w*v0.w
                + v1.x*v1.x + v1.y*v1.y + v1.z*v1.z + v1.w*v1.w;
      s2 += __shfl_xor(s2, 1);  s2 += __shfl_xor(s2, 2);
      s2 += __shfl_xor(s2, 4);  s2 += __shfl_xor(s2, 8);
      sq2 += __shfl_xor(sq2, 1); sq2 += __shfl_xor(sq2, 2);
      sq2 += __shfl_xor(sq2, 4); sq2 += __shfl_xor(sq2, 8);
      const float m2 = s2 * (1.f/128.f);
      const float rs2 = rsqrtf(sq2*(1.f/128.f) - m2*m2 + 1e-5f);
      const float4 gc0 = *(const float4*)(g2 + le);
      const float4 gc1 = *(const float4*)(g2 + le + 4);
      const float4 bc0 = *(const float4*)(b2 + le);
      const float4 bc1 = *(const float4*)(b2 + le + 4);
      ushort8v pa;
      pa[0] = f2bf((v0.x - m2)*rs2*gc0.x + bc0.x);
      pa[1] = f2bf((v0.y - m2)*rs2*gc0.y + bc0.y);
      pa[2] = f2bf((v0.z - m2)*rs2*gc0.z + bc0.z);
      pa[3] = f2bf((v0.w - m2)*rs2*gc0.w + bc0.w);
      pa[4] = f2bf((v1.x - m2)*rs2*gc1.x + bc1.x);
      pa[5] = f2bf((v1.y - m2)*rs2*gc1.y + bc1.y);
      pa[6] = f2bf((v1.z - m2)*rs2*gc1.z + bc1.z);
      pa[7] = f2bf((v1.w - m2)*rs2*gc1.w + bc1.w);
      *(ushort8v*)&Atile[lr][le] = pa;
    } else {
      const ushort8v zz = {};
      *(ushort8v*)&Atile[lr][le] = zz;
    }
  }
  __syncthreads();                       // [bar 1]

  // --- P2: in_proj GEMM; wave w owns n-cols w*64..w*64+63, BOTH m-tiles ---
  {
    short8 af[2][4];
    #pragma unroll
    for (int mt = 0; mt < 2; mt++)
      #pragma unroll
      for (int ks = 0; ks < 4; ks++)
        af[mt][ks] = *(const short8*)&Atile[mt*16 + l16][ks*32 + quad*8];
    const int nb = wave * 64;
    #pragma unroll
    for (int j = 0; j < 4; j++) {
      const int ncol = nb + j*16;
      floatx4 acc0 = {}, acc1 = {};
      #pragma unroll
      for (int ks = 0; ks < 4; ks++) {
        short8 bv = *(const short8*)(wb_in + (size_t)(ncol + l16)*DD + ks*32 + quad*8);
        acc0 = __builtin_amdgcn_mfma_f32_16x16x32_bf16(af[0][ks], bv, acc0, 0, 0, 0);
        acc1 = __builtin_amdgcn_mfma_f32_16x16x32_bf16(af[1][ks], bv, acc1, 0, 0, 0);
      }
      const int coll = ncol + l16;
      if (nb < 256) {
        #pragma unroll
        for (int rr = 0; rr < 4; rr++)
          ubuf[quad*4 + rr][coll] = acc0[rr];       // rows 0..15 all < 19
        #pragma unroll
        for (int rr = 0; rr < 4; rr++) {
          const int m = 16 + quad*4 + rr;
          if (m < 19) ubuf[m][coll] = acc1[rr];
        }
      } else {
        const int gcol = coll - 256;
        #pragma unroll
        for (int rr = 0; rr < 4; rr++) {
          const int m = quad*4 + rr;
          if (m >= 3) {
            const float v = acc0[rr];
            gate[(size_t)(t0 + m - 3)*ED + gcol] = v / (1.f + __expf(-v));
          }
        }
        #pragma unroll
        for (int rr = 0; rr < 4; rr++) {
          const int m = 16 + quad*4 + rr;
          if (m < 19) {
            const float v = acc1[rr];
            gate[(size_t)(t0 + m - 3)*ED + gcol] = v / (1.f + __expf(-v));
          }
        }
      }
    }
  }
  __syncthreads();                       // [bar 2] ubuf ready; Atile reads done

  // --- conv+silu: thread = (ch, 8-token group) -> As (overlays Atile) ---
  {
    const int ch = tid & 255, tg = tid >> 8;
    const int i0 = tg * 8;
    const float4 w = *(const float4*)(cw + ch*4);
    const float cbe = cb[ch];
    float v0 = ubuf[i0][ch], v1 = ubuf[i0+1][ch], v2 = ubuf[i0+2][ch];
    #pragma unroll
    for (int k = 0; k < 8; k++) {
      const float cur = ubuf[i0+3+k][ch];
      const float a = cbe + v0*w.x + v1*w.y + v2*w.z + cur*w.w;
      const float s = a / (1.f + __expf(-a));
      const int i = i0 + k;
      As[i][ch] = f2bf(s);
      sus[i][ch] = s;
      uc[(size_t)(t0+i)*ED + ch] = s;
      v0 = v1; v1 = v2; v2 = cur;
    }
  }
  __syncthreads();                       // [bar 3] As/sus ready; ubuf dead

  // --- xproj MFMA M=16, N=40, K=256; waves 0-2; B direct from global ---
  if (wave < 3) {
    const int jn = (wave == 2) ? 24 : wave*16;
    floatx4 acc = {};
    #pragma unroll
    for (int ks = 0; ks < 8; ks++) {
      const int ko = ks*32 + quad*8;
      short8 a  = *(const short8*)&As[l16][ko];
      short8 bv = *(const short8*)(wb_xp + (size_t)(jn + l16)*ED + ko);
      acc = __builtin_amdgcn_mfma_f32_16x16x32_bf16(a, bv, acc, 0, 0, 0);
    }
    const int n = jn + l16;
    if (wave < 2 || l16 >= 8) {          // drop duplicated n=24..31
      #pragma unroll
      for (int rr = 0; rr < 4; rr++) {
        const int m = quad*4 + rr;
        sdbc[m][n] = acc[rr];
        dbc[(size_t)(t0 + m)*40 + n] = acc[rr];
      }
    }
  }
  __syncthreads();                       // [bar 4]

  // --- P5+P6: delta (cheap softplus) + chunk scan summary; prefetched ---
  {
    const int e = tid >> 1, half = tid & 1;
    const int n0 = half * 8;
    const float4 dw0 = *(const float4*)(dtw + e*RR);
    const float4 dw1 = *(const float4*)(dtw + e*RR + 4);
    const float db = dtb[e];
    const float4 a0 = *(const float4*)(A_log + e*NN + n0);
    const float4 a1 = *(const float4*)(A_log + e*NN + n0 + 4);
    float Aen[8] = {-__expf(a0.x)*LOG2E, -__expf(a0.y)*LOG2E,
                    -__expf(a0.z)*LOG2E, -__expf(a0.w)*LOG2E,
                    -__expf(a1.x)*LOG2E, -__expf(a1.y)*LOG2E,
                    -__expf(a1.z)*LOG2E, -__expf(a1.w)*LOG2E};
    float h[8] = {};
    float sumd = 0.f;
    // 1-token-ahead register prefetch of the scan-chain LDS reads
    float4 q0 = *(const float4*)&sdbc[0][0];
    float4 q1 = *(const float4*)&sdbc[0][4];
    float4 B0 = *(const float4*)&sdbc[0][RR + n0];
    float4 B1 = *(const float4*)&sdbc[0][RR + n0 + 4];
    float su = sus[0][e];
    for (int t = 0; t < LCS; t++) {
      const float4 cq0 = q0, cq1 = q1, cB0 = B0, cB1 = B1;
      const float csu = su;
      if (t < LCS-1) {
        q0 = *(const float4*)&sdbc[t+1][0];
        q1 = *(const float4*)&sdbc[t+1][4];
        B0 = *(const float4*)&sdbc[t+1][RR + n0];
        B1 = *(const float4*)&sdbc[t+1][RR + n0 + 4];
        su = sus[t+1][e];
      }
      const float aa = db
          + cq0.x*dw0.x + cq0.y*dw0.y + cq0.z*dw0.z + cq0.w*dw0.w
          + cq1.x*dw1.x + cq1.y*dw1.y + cq1.z*dw1.z + cq1.w*dw1.w;
      float dv;
      if (aa > 20.f) dv = aa;
      else {
        const float et = exp2_fast(aa * LOG2E);       // e^aa
        dv = __log2f(1.f + et) * LN2F;                // ln(1+e^aa)
      }
      if (half == 0) delta[(size_t)(t0+t)*ED + e] = dv;
      const float du = dv * csu;
      const float Bv[8] = {cB0.x,cB0.y,cB0.z,cB0.w, cB1.x,cB1.y,cB1.z,cB1.w};
      sumd += dv;
      #pragma unroll
      for (int j = 0; j < 8; j++)
        h[j] = exp2_fast(dv * Aen[j])*h[j] + Bv[j]*du;
    }
    const size_t base = (((size_t)c2*BB + b)*ED + e)*NN + n0;
    *(float4*)(cA + base)     = make_float4(exp2_fast(sumd*Aen[0]), exp2_fast(sumd*Aen[1]),
                                            exp2_fast(sumd*Aen[2]), exp2_fast(sumd*Aen[3]));
    *(float4*)(cA + base + 4) = make_float4(exp2_fast(sumd*Aen[4]), exp2_fast(sumd*Aen[5]),
                                            exp2_fast(sumd*Aen[6]), exp2_fast(sumd*Aen[7]));
    *(float4*)(cH + base)     = make_float4(h[0], h[1], h[2], h[3]);
    *(float4*)(cH + base + 4) = make_float4(h[4], h[5], h[6], h[7]);
  }
}

// ---------------------------------------------------------------------------
// Scan phase 2: 8-way segmented over NCS=256 chunks (unchanged from r8).
// ---------------------------------------------------------------------------
__global__ __launch_bounds__(256) void scan2p8_k(float* __restrict__ cA,
    const float* __restrict__ cH) {
  const int gt = blockIdx.x*256 + threadIdx.x;  // [0, 8*BB*ED*NN)
  const int scan = gt >> 3;                     // [0, BB*ED*NN)
  const int seg  = gt & 7;
  const int lane = threadIdx.x & 63;
  const int lb   = lane & ~7;
  const int b = scan >> 12;
  const size_t base = (size_t)b*ED*NN + (scan & 4095);
  const int c0 = seg * 32;

  float ap = 1.f, hs = 0.f;
  for (int g = 0; g < 2; g++) {
    float av[16], hv[16];
    #pragma unroll
    for (int i = 0; i < 16; i++) {
      const size_t idx = (size_t)(c0 + g*16 + i)*(BB*ED*NN) + base;
      av[i] = cA[idx]; hv[i] = cH[idx];
    }
    #pragma unroll
    for (int i = 0; i < 16; i++) {
      hs = av[i]*hs + hv[i];
      ap *= av[i];
    }
  }
  float h = 0.f;
  #pragma unroll
  for (int k = 0; k < 7; k++) {
    const float ak = __shfl(ap, lb + k);
    const float hk = __shfl(hs, lb + k);
    if (seg > k) h = ak*h + hk;
  }
  for (int g = 0; g < 2; g++) {
    float av[16], hv[16];
    #pragma unroll
    for (int i = 0; i < 16; i++) {
      const size_t idx = (size_t)(c0 + g*16 + i)*(BB*ED*NN) + base;
      av[i] = cA[idx]; hv[i] = cH[idx];
    }
    #pragma unroll
    for (int i = 0; i < 16; i++) {
      const size_t idx = (size_t)(c0 + g*16 + i)*(BB*ED*NN) + base;
      cA[idx] = h;
      h = av[i]*h + hv[i];
    }
  }
}

// ---------------------------------------------------------------------------
// tail9: unchanged from round 8 (direct-global bf16 B-fragments, 6 barriers).
// ---------------------------------------------------------------------------
__global__ __launch_bounds__(1024) void tail9_k(
    const float* __restrict__ gate, const float* __restrict__ delta,
    const float* __restrict__ uc, const float* __restrict__ dbc,
    const float* __restrict__ cP, const float* __restrict__ A_log,
    const float* __restrict__ Dpv, const float* __restrict__ x,
    const float* __restrict__ g1, const float* __restrict__ b1,
    const unsigned short* __restrict__ wb_out,
    const unsigned short* __restrict__ wb_f1,
    const unsigned short* __restrict__ wb_f2,
    const float* __restrict__ fc1_b, const float* __restrict__ fc2_b,
    float* __restrict__ out) {
  __shared__ __align__(16) unsigned short Au[32][264];  // y -> hln -> h (bf16)
  __shared__ float xs[32][132];                         // xnew tile fp32
  __shared__ float sbc[32][32];                         // B/C rows (LDS bcast)

  const int c = blockIdx.x, b = blockIdx.y;
  const int t0 = b*LL + c*LC;
  const int tid = threadIdx.x;
  const int wave = tid >> 6, lane = tid & 63;
  const int quad = lane >> 4, l16 = lane & 15;

  if (tid < 256) {
    const int row = tid >> 3, c4 = (tid & 7) * 4;
    *(float4*)&sbc[row][c4] = *(const float4*)(dbc + (size_t)(t0 + row)*40 + RR + c4);
  }
  __syncthreads();                       // [bar 1]

  {
    const int e = tid >> 2, q = tid & 3;
    const int n0 = q * 4;
    float Aen[4], h[4];
    {
      const float4 a0 = *(const float4*)(A_log + e*NN + n0);
      Aen[0]=-__expf(a0.x)*LOG2E; Aen[1]=-__expf(a0.y)*LOG2E;
      Aen[2]=-__expf(a0.z)*LOG2E; Aen[3]=-__expf(a0.w)*LOG2E;
      const float4 h0 = *(const float4*)(cP + (((size_t)(2*c)*BB + b)*ED + e)*NN + n0);
      h[0]=h0.x; h[1]=h0.y; h[2]=h0.z; h[3]=h0.w;
    }
    const float Dpe = Dpv[e];
    float pd[8], pu[8], pg[8];
    #pragma unroll
    for (int i = 0; i < 8; i++) {
      pd[i] = delta[(size_t)(t0+i)*ED + e];
      pu[i] = uc[(size_t)(t0+i)*ED + e];
      pg[i] = gate[(size_t)(t0+i)*ED + e];
    }
    for (int g4 = 0; g4 < 4; g4++) {
      float cd[8], cu[8], cg[8];
      #pragma unroll
      for (int i = 0; i < 8; i++) { cd[i]=pd[i]; cu[i]=pu[i]; cg[i]=pg[i]; }
      if (g4 < 3) {
        const int tn = t0 + (g4+1)*8;
        #pragma unroll
        for (int i = 0; i < 8; i++) {
          pd[i] = delta[(size_t)(tn+i)*ED + e];
          pu[i] = uc[(size_t)(tn+i)*ED + e];
          pg[i] = gate[(size_t)(tn+i)*ED + e];
        }
      }
      #pragma unroll
      for (int i = 0; i < 8; i++) {
        const int t = g4*8 + i;
        const float dv = cd[i];
        const float uv = cu[i];
        const float du = dv * uv;
        const float4 B0 = *(const float4*)&sbc[t][n0];
        const float4 C0 = *(const float4*)&sbc[t][16 + n0];
        const float Bv[4] = {B0.x,B0.y,B0.z,B0.w};
        const float Cv[4] = {C0.x,C0.y,C0.z,C0.w};
        float part = 0.f;
        #pragma unroll
        for (int j = 0; j < 4; j++) {
          h[j] = exp2_fast(dv * Aen[j])*h[j] + Bv[j]*du;
          part += h[j]*Cv[j];
        }
        part += __shfl_xor(part, 1);
        part += __shfl_xor(part, 2);
        if (q == 0)
          Au[t][e] = f2bf((part + uv*Dpe) * cg[i]);
      }
    }
  }
  __syncthreads();                       // [bar 2]

  {
    const int mi = (wave & 1) * 16;
    const int wn = (wave >> 1) * 16;
    floatx4 acc = {};
    #pragma unroll
    for (int ks = 0; ks < 8; ks++) {
      const int ko = ks*32 + quad*8;
      short8 a  = *(const short8*)&Au[mi + l16][ko];
      short8 bv = *(const short8*)(wb_out + (size_t)(wn + l16)*ED + ko);
      acc = __builtin_amdgcn_mfma_f32_16x16x32_bf16(a, bv, acc, 0, 0, 0);
    }
    const int n = wn + l16;
    #pragma unroll
    for (int r = 0; r < 4; r++) {
      const int m = mi + quad*4 + r;
      xs[m][n] = acc[r] + x[(size_t)(t0 + m)*DD + n];
    }
  }
  __syncthreads();                       // [bar 3]

  if (tid < 512) {
    const int lr = tid >> 4, le = (tid & 15) * 8;
    float vv[8];
    float s = 0.f, sq = 0.f;
    #pragma unroll
    for (int i = 0; i < 8; i++) {
      vv[i] = xs[lr][le + i];
      s += vv[i]; sq += vv[i]*vv[i];
    }
    s += __shfl_xor(s, 1);  s += __shfl_xor(s, 2);
    s += __shfl_xor(s, 4);  s += __shfl_xor(s, 8);
    sq += __shfl_xor(sq, 1); sq += __shfl_xor(sq, 2);
    sq += __shfl_xor(sq, 4); sq += __shfl_xor(sq, 8);
    const float mean = s * (1.f/128.f);
    const float rs = rsqrtf(sq*(1.f/128.f) - mean*mean + 1e-5f);
    ushort8v p;
    #pragma unroll
    for (int i = 0; i < 8; i++)
      p[i] = f2bf((vv[i] - mean)*rs*g1[le + i] + b1[le + i]);
    *(ushort8v*)&Au[lr][le] = p;
  }
  __syncthreads();                       // [bar 4]

  {
    const int mi = (wave & 1) * 16;
    const int wn = (wave >> 1) * 32;
    floatx4 acc[2] = {};
    #pragma unroll
    for (int ks = 0; ks < 4; ks++) {
      const int ko = ks*32 + quad*8;
      short8 a  = *(const short8*)&Au[mi + l16][ko];
      short8 b0 = *(const short8*)(wb_f1 + (size_t)(wn +      l16)*DD + ko);
      short8 b1v= *(const short8*)(wb_f1 + (size_t)(wn + 16 + l16)*DD + ko);
      acc[0] = __builtin_amdgcn_mfma_f32_16x16x32_bf16(a, b0, acc[0], 0, 0, 0);
      acc[1] = __builtin_amdgcn_mfma_f32_16x16x32_bf16(a, b1v, acc[1], 0, 0, 0);
    }
    __syncthreads();                     // [bar 5] all hln reads done
    #pragma unroll
    for (int f = 0; f < 2; f++) {
      const int n = wn + f*16 + l16;
      const float bn = fc1_b[n];
      #pragma unroll
      for (int r = 0; r < 4; r++) {
        const int m = mi + quad*4 + r;
        float v = acc[f][r] + bn;
        v = 0.5f*v*(1.f + erff(v*0.70710678118f));
        Au[m][n] = f2bf(v);
      }
    }
  }
  __syncthreads();                       // [bar 6]

  {
    const int mi = (wave & 1) * 16;
    const int wn = (wave >> 1) * 16;
    floatx4 acc = {};
    #pragma unroll
    for (int ks = 0; ks < 8; ks++) {
      const int ko = ks*32 + quad*8;
      short8 a  = *(const short8*)&Au[mi + l16][ko];
      short8 bv = *(const short8*)(wb_f2 + (size_t)(wn + l16)*HH + ko);
      acc = __builtin_amdgcn_mfma_f32_16x16x32_bf16(a, bv, acc, 0, 0, 0);
    }
    const int n = wn + l16;
    const float bn = fc2_b[n];
    #pragma unroll
    for (int r = 0; r < 4; r++) {
      const int m = mi + quad*4 + r;
      out[(size_t)(t0 + m)*DD + n] = acc[r] + bn + xs[m][n];
    }
  }
}

// ---------------------------------------------------------------------------
extern "C" void kernel_launch(void* const* d_in, const int* in_sizes, int n_in,
                              void* d_out, int out_size, void* d_ws, size_t ws_size,
                              hipStream_t stream) {
  const float* x      = (const float*)d_in[0];
  const float* n1g    = (const float*)d_in[1];
  const float* n1b    = (const float*)d_in[2];
  const float* ing    = (const float*)d_in[3];
  const float* inb    = (const float*)d_in[4];
  const float* in_w   = (const float*)d_in[5];
  const float* conv_w = (const float*)d_in[6];
  const float* conv_b = (const float*)d_in[7];
  const float* xproj_w= (const float*)d_in[8];
  const float* dt_w   = (const float*)d_in[9];
  const float* dt_b   = (const float*)d_in[10];
  const float* A_log  = (const float*)d_in[11];
  const float* Dpv    = (const float*)d_in[12];
  const float* out_w  = (const float*)d_in[13];
  const float* fc1_w  = (const float*)d_in[14];
  const float* fc1_b  = (const float*)d_in[15];
  const float* fc2_w  = (const float*)d_in[16];
  const float* fc2_b  = (const float*)d_in[17];
  float* out = (float*)d_out;

  // Workspace (~42 MB)
  float* ws    = (float*)d_ws;
  float* uc    = ws;                          // [NT,256]
  float* dbc   = uc    + (size_t)NT*ED;       // [NT,40]
  float* delta = dbc   + (size_t)NT*40;       // [NT,256]
  float* gate  = delta + (size_t)NT*ED;       // [NT,256]  silu(z)
  float* cA    = gate  + (size_t)NT*ED;       // [NCS,B,ED,N]
  float* cH    = cA    + (size_t)NCS*BB*ED*NN;
  unsigned short* wb = (unsigned short*)(cH + (size_t)NCS*BB*ED*NN);
  unsigned short* wb_in  = wb;                // [512][128]
  unsigned short* wb_xp  = wb_in  + S_IN;     // [40][256]
  unsigned short* wb_out = wb_xp  + S_XP;     // [128][256]
  unsigned short* wb_f1  = wb_out + S_OUT;    // [256][128]
  unsigned short* wb_f2  = wb_f1  + S_F1;     // [128][256]

  // 0) one-time weight fp32->bf16 conversion (L2-resident thereafter)
  prep_k<<<(S_IN+S_XP+S_OUT+S_F1+S_F2)/(256*8), 256, 0, stream>>>(
      in_w, xproj_w, out_w, fc1_w, fc2_w, wb);
  // 1) fused LN+in_proj+conv+xproj+delta+summaries
  scan1n_k<<<dim3(NCS, BB), 512, 0, stream>>>(x, n1g, n1b, ing, inb, wb_in,
                                              conv_w, conv_b, wb_xp, dt_w, dt_b,
                                              A_log, uc, dbc, delta, gate, cA, cH);
  // 2) inter-chunk prefix (8-way segmented over 256 chunks)
  scan2p8_k<<<(8*BB*ED*NN)/256, 256, 0, stream>>>(cA, cH);
  // 3) scan replay + gate + out_proj + LN + MLP + residuals -> out
  tail9_k<<<dim3(NC, BB), 1024, 0, stream>>>(gate, delta, uc, dbc, cA, A_log, Dpv,
                                             x, n1g, n1b, wb_out, wb_f1, wb_f2,
                                             fc1_b, fc2_b, out);
}